// Round 1
// baseline (11991.743 us; speedup 1.0000x reference)
//
#include <hip/hip_runtime.h>
#include <hip/hip_bf16.h>
#include <stdint.h>

typedef __attribute__((ext_vector_type(8))) short short8;
typedef __attribute__((ext_vector_type(4))) short short4v;
typedef __attribute__((ext_vector_type(4))) float f32x4;
using bf16 = __hip_bfloat16;

__device__ __forceinline__ float bfb2f(unsigned short u) {
  union { unsigned u; float f; } x; x.u = ((unsigned)u) << 16; return x.f;
}
__device__ __forceinline__ unsigned short f2bfb(float f) {
  union { float f; unsigned u; } x; x.f = f;
  unsigned r = x.u + 0x7FFFu + ((x.u >> 16) & 1u);
  return (unsigned short)(r >> 16);
}
__device__ __forceinline__ float sigf(float x) { return 1.0f / (1.0f + __expf(-x)); }
__device__ __forceinline__ float tanhf_(float x) {
  x = fminf(fmaxf(x, -15.f), 15.f);
  float e = __expf(2.f * x);
  return 1.f - 2.f / (e + 1.f);
}
__device__ __forceinline__ f32x4 mfma16(short8 a, short8 b, f32x4 c) {
  return __builtin_amdgcn_mfma_f32_16x16x32_bf16(a, b, c, 0, 0, 0);
}
// XOR swizzle on 16B granules: spreads 64B-stride rows across banks (G4/T2)
__device__ __forceinline__ int swz(int b) { return b ^ (((b >> 6) & 7) << 4); }

// ---------------- prep / packing kernels ----------------

// Apack[s][co][ci] = w[co][ci][dy][dx], s = dy*3+dx
__global__ void k_pack_apack(const float* __restrict__ w, bf16* __restrict__ out, int CO, int CI) {
  int idx = blockIdx.x * 256 + threadIdx.x;
  int total = 9 * CO * CI;
  if (idx >= total) return;
  int ci = idx % CI; int r = idx / CI; int co = r % CO; int s = r / CO;
  ((unsigned short*)out)[(s * CO + co) * CI + ci] = f2bfb(w[(co * CI + ci) * 9 + s]);
}

__global__ void k_cast(const float* __restrict__ src, bf16* __restrict__ dst, int n) {
  int idx = blockIdx.x * 256 + threadIdx.x;
  if (idx < n) ((unsigned short*)dst)[idx] = f2bfb(src[idx]);
}

// WvT[n*512+k] = Wv[k*512+n]
__global__ void k_castT512(const float* __restrict__ src, bf16* __restrict__ dst) {
  int idx = blockIdx.x * 256 + threadIdx.x;
  if (idx >= 262144) return;
  int k = idx >> 9, nn = idx & 511;
  ((unsigned short*)dst)[nn * 512 + k] = f2bfb(src[idx]);
}

// B-fragment-packed layouts: P[((jblk*KG + kg)*16 + jc)*8 + kj], k=kg*8+kj, j=jblk*16+jc
// Gates B: K=1120 rows = [Wx[:, :80] | 16 zero | Wx[:, 80:592] | Wh], N=2048
__global__ void k_pack_wg(const float* __restrict__ Wx, const float* __restrict__ Wh, bf16* __restrict__ out) {
  int idx = blockIdx.x * 256 + threadIdx.x;
  if (idx >= 2293760) return;
  int kj = idx & 7, jc = (idx >> 3) & 15; int r = idx >> 7;
  int kg = r % 140, jblk = r / 140;
  int k = kg * 8 + kj, j = jblk * 16 + jc;
  float v = 0.f;
  if (k < 80) v = Wx[j * 592 + k];
  else if (k < 96) v = 0.f;
  else if (k < 608) v = Wx[j * 592 + k - 16];
  else v = Wh[j * 512 + k - 608];
  ((unsigned short*)out)[idx] = f2bfb(v);
}
// O-proj B: B(k,o) = W_O[o][k], K=1024, N=512
__global__ void k_pack_wo(const float* __restrict__ WO, bf16* __restrict__ out) {
  int idx = blockIdx.x * 256 + threadIdx.x;
  if (idx >= 524288) return;
  int kj = idx & 7, jc = (idx >> 3) & 15; int r = idx >> 7;
  int kg = r % 128, jblk = r / 128;
  int k = kg * 8 + kj, o = jblk * 16 + jc;
  ((unsigned short*)out)[idx] = f2bfb(WO[o * 1024 + k]);
}
// vocab B: B(k,v) = W_out[v][k], K=512, N=512 (cols >=500 zero)
__global__ void k_pack_wout(const float* __restrict__ W, bf16* __restrict__ out) {
  int idx = blockIdx.x * 256 + threadIdx.x;
  if (idx >= 262144) return;
  int kj = idx & 7, jc = (idx >> 3) & 15; int r = idx >> 7;
  int kg = r % 64, jblk = r / 64;
  int k = kg * 8 + kj, v = jblk * 16 + jc;
  ((unsigned short*)out)[idx] = (v < 500) ? f2bfb(W[v * 512 + k]) : (unsigned short)0;
}

// X = [emb(80)+pad16 | O(512)] rows of 608; Hbuf 2 slots; c state zero
__global__ void k_init(bf16* __restrict__ X, bf16* __restrict__ Hb, float* __restrict__ Cst,
                       const bf16* __restrict__ Ebf) {
  int idx = blockIdx.x * 256 + threadIdx.x;
  if (idx < 32 * 608) {
    int k = idx % 608;
    unsigned short v = 0;
    if (k < 80) v = ((const unsigned short*)Ebf)[497 * 80 + k];  // start token = vocab-3
    ((unsigned short*)X)[idx] = v;
  }
  if (idx < 32768) ((unsigned short*)Hb)[idx] = 0;
  if (idx < 16384) Cst[idx] = 0.f;
}

// ---------------- CNN ----------------

// conv1 (Ci=1) direct fp32 + relu + 2x2 pool, writes padded NHWC bf16 [32][34][258][64]
__global__ __launch_bounds__(256) void k_conv1(const float* __restrict__ Xin, const float* __restrict__ w1,
                                               const float* __restrict__ b1, bf16* __restrict__ out) {
  __shared__ float wsm[576];
  __shared__ float xt[4][10];
  const int tid = threadIdx.x;
  const int n = blockIdx.z, y2 = blockIdx.y, xb = blockIdx.x * 4;
  for (int i = tid; i < 576; i += 256) wsm[i] = w1[i];
  if (tid < 40) {
    int rr = tid / 10, cc = tid % 10;
    int gy = 2 * y2 - 1 + rr, gx = 2 * xb - 1 + cc;
    float v = 0.f;
    if (gy >= 0 && gy < 64 && gx >= 0 && gx < 512) v = Xin[n * 32768 + gy * 512 + gx];
    xt[rr][cc] = v;
  }
  __syncthreads();
  const int co = tid & 63, xl = tid >> 6;
  const float bb = b1[co];
  float mx = 0.f;
#pragma unroll
  for (int py = 0; py < 2; ++py)
#pragma unroll
    for (int px = 0; px < 2; ++px) {
      float s = bb;
#pragma unroll
      for (int dy = 0; dy < 3; ++dy)
#pragma unroll
        for (int dx = 0; dx < 3; ++dx)
          s = fmaf(wsm[co * 9 + dy * 3 + dx], xt[py + dy][2 * xl + px + dx], s);
      mx = fmaxf(mx, fmaxf(s, 0.f));
    }
  ((unsigned short*)out)[((n * 34 + y2 + 1) * 258 + (xb + xl) + 1) * 64 + co] = f2bfb(mx);
}

// conv as 9-shift GEMM: A=Apack[s] (Co x Ci), B=padded NHWC input (Ci x pixels), fp32 acc, relu
// MODE 0: out[pixel][co] (pre-pool buffer). MODE 1: out = padded NHWC (no pool, conv3).
template <int CI, int CO, int H, int W, int MODE>
__global__ __launch_bounds__(256) void k_convgemm(const bf16* __restrict__ inP, const bf16* __restrict__ apack,
                                                  const float* __restrict__ bias, bf16* __restrict__ outp) {
  constexpr int Hp = H + 2, Wp = W + 2;
  __shared__ __align__(16) char As[8192];
  __shared__ __align__(16) char Bs[8192];
  const int tid = threadIdx.x, lane = tid & 63, wv = tid >> 6;
  const int lm = lane & 15, kh = lane >> 4;
  const int wm = wv & 1, wn = wv >> 1;
  const int p0 = blockIdx.x * 128, m0 = blockIdx.y * 128;
  const int n = p0 / (H * W), rem = p0 % (H * W);
  const int y = rem / W, x0 = rem % W;
  const long long pixbase = ((long long)(n * Hp + y) * Wp + x0) * CI;
  f32x4 acc[4][4];
#pragma unroll
  for (int i = 0; i < 4; ++i)
#pragma unroll
    for (int j = 0; j < 4; ++j) acc[i][j] = (f32x4){0.f, 0.f, 0.f, 0.f};
  const int r = tid >> 1, e0 = (tid & 1) * 16;
  const int wb = r * 64 + e0 * 2;  // LDS byte offset base for staging
  for (int s = 0; s < 9; ++s) {
    const int dy = s / 3, dx = s % 3;
    const bf16* bsrc = inP + pixbase + (dy * Wp + dx) * CI;
    const bf16* asrc = apack + (s * CO + m0) * CI;
    for (int cc = 0; cc < CI / 32; ++cc) {
      short8 av0 = *(const short8*)(asrc + r * CI + cc * 32 + e0);
      short8 av1 = *(const short8*)(asrc + r * CI + cc * 32 + e0 + 8);
      short8 bv0 = *(const short8*)(bsrc + (long long)r * CI + cc * 32 + e0);
      short8 bv1 = *(const short8*)(bsrc + (long long)r * CI + cc * 32 + e0 + 8);
      __syncthreads();
      *(short8*)(void*)(As + swz(wb)) = av0;
      *(short8*)(void*)(As + swz(wb + 16)) = av1;
      *(short8*)(void*)(Bs + swz(wb)) = bv0;
      *(short8*)(void*)(Bs + swz(wb + 16)) = bv1;
      __syncthreads();
      short8 af[4], bg[4];
#pragma unroll
      for (int i = 0; i < 4; ++i)
        af[i] = *(const short8*)(const void*)(As + swz((wm * 64 + i * 16 + lm) * 64 + kh * 16));
#pragma unroll
      for (int j = 0; j < 4; ++j)
        bg[j] = *(const short8*)(const void*)(Bs + swz((wn * 64 + j * 16 + lm) * 64 + kh * 16));
#pragma unroll
      for (int i = 0; i < 4; ++i)
#pragma unroll
        for (int j = 0; j < 4; ++j) acc[i][j] = mfma16(af[i], bg[j], acc[i][j]);
    }
  }
  // epilogue: D row = co (M), col = pixel (N); 4 consecutive co per lane -> 8B store
#pragma unroll
  for (int i = 0; i < 4; ++i) {
    const int co = m0 + wm * 64 + i * 16 + kh * 4;
    float b4[4];
#pragma unroll
    for (int rr = 0; rr < 4; ++rr) b4[rr] = bias[co + rr];
#pragma unroll
    for (int j = 0; j < 4; ++j) {
      const int pix = p0 + wn * 64 + j * 16 + lm;
      short4v pk;
#pragma unroll
      for (int rr = 0; rr < 4; ++rr) {
        float v = fmaxf(acc[i][j][rr] + b4[rr], 0.f);
        pk[rr] = (short)f2bfb(v);
      }
      if constexpr (MODE == 0) {
        *(short4v*)(void*)(outp + (long long)pix * CO + co) = pk;
      } else {
        const int nn = pix / (H * W), r2 = pix % (H * W);
        const int yy = r2 / W, xx = r2 % W;
        *(short4v*)(void*)(outp + ((long long)(nn * Hp + yy + 1) * Wp + xx + 1) * CO + co) = pk;
      }
    }
  }
}

// 2x2 max pool on NHWC bf16, write with optional +1 padding offset
__global__ void k_pool(const bf16* __restrict__ src, bf16* __restrict__ dst,
                       int H, int W, int C, int OHP, int OWP, int pad) {
  const int idx = blockIdx.x * 256 + threadIdx.x;
  const int C8 = C >> 3;
  const int c8 = idx % C8; int tmp = idx / C8;
  const int x2 = tmp % (W >> 1); tmp /= (W >> 1);
  const int y2 = tmp % (H >> 1); const int n = tmp / (H >> 1);
  if (n >= 32) return;
  const long long sbase = ((long long)(n * H + 2 * y2) * W + 2 * x2) * C + c8 * 8;
  short8 a = *(const short8*)(src + sbase);
  short8 b = *(const short8*)(src + sbase + C);
  short8 c = *(const short8*)(src + sbase + (long long)W * C);
  short8 d = *(const short8*)(src + sbase + (long long)W * C + C);
  short8 o;
#pragma unroll
  for (int e = 0; e < 8; ++e) {
    float m = fmaxf(fmaxf(bfb2f((unsigned short)a[e]), bfb2f((unsigned short)b[e])),
                    fmaxf(bfb2f((unsigned short)c[e]), bfb2f((unsigned short)d[e])));
    o[e] = (short)f2bfb(m);
  }
  *(short8*)(void*)(dst + ((long long)(n * OHP + y2 + pad) * OWP + x2 + pad) * C + c8 * 8) = o;
}

// Vproj = V @ WvT^T-style GEMM: M=16384 (b,l), N=512, K=512, +b_att, bf16 out
__global__ __launch_bounds__(256) void k_gemm_vproj(const bf16* __restrict__ Vb, const bf16* __restrict__ WvT,
                                                    const float* __restrict__ batt, bf16* __restrict__ VP) {
  __shared__ __align__(16) char As[8192];
  __shared__ __align__(16) char Bs[8192];
  const int tid = threadIdx.x, lane = tid & 63, wv = tid >> 6;
  const int lm = lane & 15, kh = lane >> 4;
  const int wm = wv & 1, wn = wv >> 1;
  const int n0 = blockIdx.x * 128, m0 = blockIdx.y * 128;
  f32x4 acc[4][4];
#pragma unroll
  for (int i = 0; i < 4; ++i)
#pragma unroll
    for (int j = 0; j < 4; ++j) acc[i][j] = (f32x4){0.f, 0.f, 0.f, 0.f};
  const int r = tid >> 1, e0 = (tid & 1) * 16;
  const int wb = r * 64 + e0 * 2;
  for (int cc = 0; cc < 16; ++cc) {
    short8 av0 = *(const short8*)(Vb + (m0 + r) * 512 + cc * 32 + e0);
    short8 av1 = *(const short8*)(Vb + (m0 + r) * 512 + cc * 32 + e0 + 8);
    short8 bv0 = *(const short8*)(WvT + (n0 + r) * 512 + cc * 32 + e0);
    short8 bv1 = *(const short8*)(WvT + (n0 + r) * 512 + cc * 32 + e0 + 8);
    __syncthreads();
    *(short8*)(void*)(As + swz(wb)) = av0;
    *(short8*)(void*)(As + swz(wb + 16)) = av1;
    *(short8*)(void*)(Bs + swz(wb)) = bv0;
    *(short8*)(void*)(Bs + swz(wb + 16)) = bv1;
    __syncthreads();
    short8 af[4], bg[4];
#pragma unroll
    for (int i = 0; i < 4; ++i)
      af[i] = *(const short8*)(const void*)(As + swz((wm * 64 + i * 16 + lm) * 64 + kh * 16));
#pragma unroll
    for (int j = 0; j < 4; ++j)
      bg[j] = *(const short8*)(const void*)(Bs + swz((wn * 64 + j * 16 + lm) * 64 + kh * 16));
#pragma unroll
    for (int i = 0; i < 4; ++i)
#pragma unroll
      for (int j = 0; j < 4; ++j) acc[i][j] = mfma16(af[i], bg[j], acc[i][j]);
  }
#pragma unroll
  for (int i = 0; i < 4; ++i)
#pragma unroll
    for (int j = 0; j < 4; ++j) {
      const int nn = n0 + wn * 64 + j * 16 + lm;
      const float ba = batt[nn];
#pragma unroll
      for (int rr = 0; rr < 4; ++rr) {
        const int m = m0 + wm * 64 + i * 16 + kh * 4 + rr;
        ((unsigned short*)VP)[m * 512 + nn] = f2bfb(acc[i][j][rr] + ba);
      }
    }
}

// ---------------- decoder step kernels ----------------
// X rows (608): [emb 80 | pad 16 | O 512]; h in Hbuf[2][32][512] bf16 (double buffered)

// blocks 0..31: gates GEMM (M=32,N=2048,K=1120) + LSTM pointwise -> h(t),c(t)
// blocks 32..39: Q(t-1) = O(t-1) @ W_out^T -> d_out
__global__ __launch_bounds__(256) void k_step_a(int t, const bf16* __restrict__ X, bf16* __restrict__ Hb,
                                                float* __restrict__ Cst, const bf16* __restrict__ WgP,
                                                const bf16* __restrict__ WoutP, const float* __restrict__ bl,
                                                float* __restrict__ outQ) {
  const int tid = threadIdx.x, lane = tid & 63, wv = tid >> 6;
  const int lm = lane & 15, kh = lane >> 4;
  if (blockIdx.x < 32) {
    if (t >= 150) return;
    const int nb = blockIdx.x;
    const int jblk = wv * 32 + nb;
    const bf16* hprev = Hb + ((t + 1) & 1) * 16384;
    f32x4 acc0 = {0.f, 0.f, 0.f, 0.f}, acc1 = {0.f, 0.f, 0.f, 0.f};
    for (int kk = 0; kk < 19; ++kk) {
      short8 a0 = *(const short8*)(X + lm * 608 + kk * 32 + kh * 8);
      short8 a1 = *(const short8*)(X + (lm + 16) * 608 + kk * 32 + kh * 8);
      short8 b = *(const short8*)(WgP + ((jblk * 140 + kk * 4 + kh) * 16 + lm) * 8);
      acc0 = mfma16(a0, b, acc0);
      acc1 = mfma16(a1, b, acc1);
    }
    for (int kk = 19; kk < 35; ++kk) {
      short8 a0 = *(const short8*)(hprev + lm * 512 + (kk - 19) * 32 + kh * 8);
      short8 a1 = *(const short8*)(hprev + (lm + 16) * 512 + (kk - 19) * 32 + kh * 8);
      short8 b = *(const short8*)(WgP + ((jblk * 140 + kk * 4 + kh) * 16 + lm) * 8);
      acc0 = mfma16(a0, b, acc0);
      acc1 = mfma16(a1, b, acc1);
    }
    __shared__ float gl[4][32][16];
    const float bj = bl[wv * 512 + nb * 16 + lm];
#pragma unroll
    for (int rr = 0; rr < 4; ++rr) {
      gl[wv][kh * 4 + rr][lm] = acc0[rr] + bj;
      gl[wv][16 + kh * 4 + rr][lm] = acc1[rr] + bj;
    }
    __syncthreads();
    bf16* hcur = Hb + (t & 1) * 16384;
    for (int idx = tid; idx < 512; idx += 256) {
      const int b = idx >> 4, hh = idx & 15;
      const int hid = nb * 16 + hh;
      float ig = gl[0][b][hh], fg = gl[1][b][hh], gg = gl[2][b][hh], og = gl[3][b][hh];
      float c = sigf(fg) * Cst[b * 512 + hid] + sigf(ig) * tanhf_(gg);
      Cst[b * 512 + hid] = c;
      ((unsigned short*)hcur)[b * 512 + hid] = f2bfb(sigf(og) * tanhf_(c));
    }
  } else {
    if (t < 1) return;
    const int ntile = (blockIdx.x - 32) * 4 + wv;
    f32x4 acc0 = {0.f, 0.f, 0.f, 0.f}, acc1 = {0.f, 0.f, 0.f, 0.f};
    for (int kk = 0; kk < 16; ++kk) {
      short8 a0 = *(const short8*)(X + lm * 608 + 96 + kk * 32 + kh * 8);
      short8 a1 = *(const short8*)(X + (lm + 16) * 608 + 96 + kk * 32 + kh * 8);
      short8 b = *(const short8*)(WoutP + ((ntile * 64 + kk * 4 + kh) * 16 + lm) * 8);
      acc0 = mfma16(a0, b, acc0);
      acc1 = mfma16(a1, b, acc1);
    }
    const int v = ntile * 16 + lm;
    if (v < 500) {
#pragma unroll
      for (int rr = 0; rr < 4; ++rr) {
        outQ[((kh * 4 + rr) * 150 + (t - 1)) * 500 + v] = acc0[rr];
        outQ[((16 + kh * 4 + rr) * 150 + (t - 1)) * 500 + v] = acc1[rr];
      }
    }
  }
}

// per (b, 128-l chunk): recompute hW = h @ Wh_att in LDS, then scores = tanh(Vproj+hW)·beta
__global__ __launch_bounds__(256) void k_step_b(int t, const bf16* __restrict__ Hb,
                                                const bf16* __restrict__ WhattB, const bf16* __restrict__ Vproj,
                                                const float* __restrict__ beta, float* __restrict__ scores) {
  const int tid = threadIdx.x;
  const int b = blockIdx.x >> 2, lc = blockIdx.x & 3;
  __shared__ unsigned short hsh[512];
  __shared__ float hW[512];
  __shared__ float bsh[512];
  const unsigned short* hp = (const unsigned short*)(Hb + (t & 1) * 16384) + b * 512;
  for (int i = tid; i < 512; i += 256) {
    hsh[i] = hp[i];
    bsh[i] = beta[i];
  }
  __syncthreads();
  const uint32_t* wp = (const uint32_t*)WhattB;
  float s0 = 0.f, s1 = 0.f;
  for (int k = 0; k < 512; ++k) {
    const float hk = bfb2f(hsh[k]);
    const uint32_t w2 = wp[k * 256 + tid];
    s0 = fmaf(hk, bfb2f((unsigned short)(w2 & 0xFFFFu)), s0);
    s1 = fmaf(hk, bfb2f((unsigned short)(w2 >> 16)), s1);
  }
  hW[tid * 2] = s0;
  hW[tid * 2 + 1] = s1;
  __syncthreads();
  const int l = lc * 128 + (tid >> 1);
  const int half = tid & 1;
  const short8* vp = (const short8*)(Vproj + ((b * 512 + l) * 512) + half * 256);
  float acc = 0.f;
  for (int i = 0; i < 32; ++i) {
    short8 v = vp[i];
#pragma unroll
    for (int e = 0; e < 8; ++e) {
      const int be = half * 256 + i * 8 + e;
      acc = fmaf(tanhf_(bfb2f((unsigned short)v[e]) + hW[be]), bsh[be], acc);
    }
  }
  acc += __shfl_xor(acc, 1, 64);
  if (half == 0) scores[b * 512 + l] = acc;
}

// per (b, 128-c chunk): softmax over 512 l (redundant per block) + ctx = a·V
__global__ __launch_bounds__(256) void k_step_c(const float* __restrict__ scores, const bf16* __restrict__ V,
                                                bf16* __restrict__ Ct) {
  const int tid = threadIdx.x;
  const int b = blockIdx.x >> 2, cc = blockIdx.x & 3;
  const int lane = tid & 63, wv = tid >> 6;
  __shared__ float sc[512];
  __shared__ float wr1[4];
  __shared__ float wr2[4];
  __shared__ float part[2][128];
  float v0 = scores[b * 512 + tid];
  float v1 = scores[b * 512 + 256 + tid];
  float m = fmaxf(v0, v1);
#pragma unroll
  for (int off = 32; off >= 1; off >>= 1) m = fmaxf(m, __shfl_xor(m, off, 64));
  if (lane == 0) wr1[wv] = m;
  __syncthreads();
  m = fmaxf(fmaxf(wr1[0], wr1[1]), fmaxf(wr1[2], wr1[3]));
  float e0 = __expf(v0 - m), e1 = __expf(v1 - m);
  sc[tid] = e0;
  sc[tid + 256] = e1;
  float s = e0 + e1;
#pragma unroll
  for (int off = 32; off >= 1; off >>= 1) s += __shfl_xor(s, off, 64);
  if (lane == 0) wr2[wv] = s;
  __syncthreads();
  const float rz = 1.0f / (wr2[0] + wr2[1] + wr2[2] + wr2[3]);
  const int c = cc * 128 + (tid & 127);
  const int lh = tid >> 7;
  const unsigned short* vb = (const unsigned short*)V + ((b * 512 + lh * 256) * 512) + c;
  float acc = 0.f;
  for (int l = 0; l < 256; ++l) acc = fmaf(sc[lh * 256 + l], bfb2f(vb[l * 512]), acc);
  part[lh][tid & 127] = acc;
  __syncthreads();
  if (tid < 128) ((unsigned short*)Ct)[b * 512 + cc * 128 + tid] = f2bfb((part[0][tid] + part[1][tid]) * rz);
}

// O(t) = tanh([h|ctx] @ W_O^T) -> X O-section; block 0 also stages emb(t+1) into X
__global__ __launch_bounds__(256) void k_step_d(int t, bf16* __restrict__ X, const bf16* __restrict__ Hb,
                                                const bf16* __restrict__ Ct, const bf16* __restrict__ WOP,
                                                const bf16* __restrict__ Ebf, const int* __restrict__ labels) {
  const int tid = threadIdx.x, lane = tid & 63, wv = tid >> 6;
  const int lm = lane & 15, kh = lane >> 4;
  const int ntile = blockIdx.x * 4 + wv;
  const bf16* hcur = Hb + (t & 1) * 16384;
  f32x4 acc0 = {0.f, 0.f, 0.f, 0.f}, acc1 = {0.f, 0.f, 0.f, 0.f};
  for (int kk = 0; kk < 16; ++kk) {
    short8 a0 = *(const short8*)(hcur + lm * 512 + kk * 32 + kh * 8);
    short8 a1 = *(const short8*)(hcur + (lm + 16) * 512 + kk * 32 + kh * 8);
    short8 b = *(const short8*)(WOP + ((ntile * 128 + kk * 4 + kh) * 16 + lm) * 8);
    acc0 = mfma16(a0, b, acc0);
    acc1 = mfma16(a1, b, acc1);
  }
  for (int kk = 16; kk < 32; ++kk) {
    short8 a0 = *(const short8*)(Ct + lm * 512 + (kk - 16) * 32 + kh * 8);
    short8 a1 = *(const short8*)(Ct + (lm + 16) * 512 + (kk - 16) * 32 + kh * 8);
    short8 b = *(const short8*)(WOP + ((ntile * 128 + kk * 4 + kh) * 16 + lm) * 8);
    acc0 = mfma16(a0, b, acc0);
    acc1 = mfma16(a1, b, acc1);
  }
  const int o = ntile * 16 + lm;
  unsigned short* Xu = (unsigned short*)X;
#pragma unroll
  for (int rr = 0; rr < 4; ++rr) {
    Xu[(kh * 4 + rr) * 608 + 96 + o] = f2bfb(tanhf_(acc0[rr]));
    Xu[(16 + kh * 4 + rr) * 608 + 96 + o] = f2bfb(tanhf_(acc1[rr]));
  }
  if (blockIdx.x == 0 && t + 1 < 150) {
    for (int idx = tid; idx < 3072; idx += 256) {
      const int b = idx / 96, k = idx % 96;
      unsigned short val = 0;
      if (k < 80) {
        const int id = labels[b * 150 + t];  // ids[b][t+1] = labels[b][t]
        val = ((const unsigned short*)Ebf)[id * 80 + k];
      }
      Xu[b * 608 + k] = val;
    }
  }
}

// ---------------- launcher ----------------

extern "C" void kernel_launch(void* const* d_in, const int* in_sizes, int n_in,
                              void* d_out, int out_size, void* d_ws, size_t ws_size,
                              hipStream_t stream) {
  (void)in_sizes; (void)n_in; (void)out_size; (void)ws_size;
  const float* Xb = (const float*)d_in[0];
  const int* lab = (const int*)d_in[1];
  const float* w1 = (const float*)d_in[2]; const float* b1 = (const float*)d_in[3];
  const float* w2 = (const float*)d_in[4]; const float* b2 = (const float*)d_in[5];
  const float* w3 = (const float*)d_in[6]; const float* b3 = (const float*)d_in[7];
  const float* w4 = (const float*)d_in[8]; const float* b4 = (const float*)d_in[9];
  const float* E = (const float*)d_in[10];
  const float* Wx = (const float*)d_in[11]; const float* Wh = (const float*)d_in[12];
  const float* blstm = (const float*)d_in[13];
  const float* Wv = (const float*)d_in[14]; const float* Wha = (const float*)d_in[15];
  const float* bat = (const float*)d_in[16]; const float* beta = (const float*)d_in[17];
  const float* WO = (const float*)d_in[18]; const float* Wout = (const float*)d_in[19];
  float* out = (float*)d_out;
  char* ws = (char*)d_ws;

  // workspace layout (bytes, all 256-aligned); regions A/B are reused across CNN stages
  constexpr size_t oRegA = 0;                       // in1p [32][34][258][64] (35,930,112) | in3p [32][18][130][256]
  constexpr size_t sRegA = 38338560ULL;
  constexpr size_t oRegB = oRegA + sRegA;           // pre2 [262144][128] | pre4 [65536][512]
  constexpr size_t oIn2p = oRegB + 67108864ULL;     // [32][18][130][128]
  constexpr size_t oV    = oIn2p + 19169280ULL;     // [32][512][512]
  constexpr size_t oVprj = oV + 16777216ULL;
  constexpr size_t oAp2  = oVprj + 16777216ULL;
  constexpr size_t oAp3  = oAp2 + 147456ULL;
  constexpr size_t oAp4  = oAp3 + 589824ULL;
  constexpr size_t oWvT  = oAp4 + 2359296ULL;
  constexpr size_t oWgP  = oWvT + 524288ULL;
  constexpr size_t oWOP  = oWgP + 4587520ULL;
  constexpr size_t oWoutP= oWOP + 1048576ULL;
  constexpr size_t oWhatt= oWoutP + 524288ULL;
  constexpr size_t oEbf  = oWhatt + 524288ULL;
  constexpr size_t oX    = oEbf + 80128ULL;
  constexpr size_t oHb   = oX + 39168ULL;
  constexpr size_t oCst  = oHb + 65536ULL;
  constexpr size_t oSc   = oCst + 65536ULL;
  constexpr size_t oCt   = oSc + 65536ULL;        // total ~168.8 MB

  bf16* in1p = (bf16*)(ws + oRegA);
  bf16* in3p = (bf16*)(ws + oRegA);
  bf16* pre2 = (bf16*)(ws + oRegB);
  bf16* pre4 = (bf16*)(ws + oRegB);
  bf16* in2p = (bf16*)(ws + oIn2p);
  bf16* Vbuf = (bf16*)(ws + oV);
  bf16* Vprj = (bf16*)(ws + oVprj);
  bf16* Ap2 = (bf16*)(ws + oAp2);
  bf16* Ap3 = (bf16*)(ws + oAp3);
  bf16* Ap4 = (bf16*)(ws + oAp4);
  bf16* WvT = (bf16*)(ws + oWvT);
  bf16* WgP = (bf16*)(ws + oWgP);
  bf16* WOP = (bf16*)(ws + oWOP);
  bf16* WoutP = (bf16*)(ws + oWoutP);
  bf16* Whatt = (bf16*)(ws + oWhatt);
  bf16* Ebf = (bf16*)(ws + oEbf);
  bf16* X = (bf16*)(ws + oX);
  bf16* Hb = (bf16*)(ws + oHb);
  float* Cst = (float*)(ws + oCst);
  float* Sc = (float*)(ws + oSc);
  bf16* Ct = (bf16*)(ws + oCt);

  // ---- prep (runs every call: ws is re-poisoned) ----
  k_pack_apack<<<(9 * 128 * 64 + 255) / 256, 256, 0, stream>>>(w2, Ap2, 128, 64);
  k_pack_apack<<<(9 * 256 * 128 + 255) / 256, 256, 0, stream>>>(w3, Ap3, 256, 128);
  k_pack_apack<<<(9 * 512 * 256 + 255) / 256, 256, 0, stream>>>(w4, Ap4, 512, 256);
  k_castT512<<<1024, 256, 0, stream>>>(Wv, WvT);
  k_cast<<<1024, 256, 0, stream>>>(Wha, Whatt, 262144);
  k_cast<<<(40000 + 255) / 256, 256, 0, stream>>>(E, Ebf, 40000);
  k_pack_wg<<<8960, 256, 0, stream>>>(Wx, Wh, WgP);
  k_pack_wo<<<2048, 256, 0, stream>>>(WO, WOP);
  k_pack_wout<<<1024, 256, 0, stream>>>(Wout, WoutP);
  k_init<<<128, 256, 0, stream>>>(X, Hb, Cst, Ebf);

  // ---- CNN ----
  hipMemsetAsync(ws + oRegA, 0, sRegA, stream);          // zero in1p (incl. pad borders)
  hipMemsetAsync(ws + oIn2p, 0, 19169280ULL, stream);    // zero in2p
  k_conv1<<<dim3(64, 32, 32), 256, 0, stream>>>(Xb, w1, b1, in1p);
  k_convgemm<64, 128, 32, 256, 0><<<dim3(2048, 1), 256, 0, stream>>>(in1p, Ap2, b2, pre2);
  k_pool<<<4096, 256, 0, stream>>>(pre2, in2p, 32, 256, 128, 18, 130, 1);
  hipMemsetAsync(ws + oRegA, 0, sRegA, stream);          // re-zero region A for in3p pads
  k_convgemm<128, 256, 16, 128, 1><<<dim3(512, 2), 256, 0, stream>>>(in2p, Ap3, b3, in3p);
  k_convgemm<256, 512, 16, 128, 0><<<dim3(512, 4), 256, 0, stream>>>(in3p, Ap4, b4, pre4);
  k_pool<<<4096, 256, 0, stream>>>(pre4, Vbuf, 16, 128, 512, 8, 64, 0);  // -> V (b,l,c)
  k_gemm_vproj<<<dim3(4, 128), 256, 0, stream>>>(Vbuf, WvT, bat, Vprj);

  // ---- decoder: 150 sequential steps ----
  for (int t = 0; t <= 150; ++t) {
    k_step_a<<<40, 256, 0, stream>>>(t, X, Hb, Cst, WgP, WoutP, blstm, out);
    if (t == 150) break;
    k_step_b<<<128, 256, 0, stream>>>(t, Hb, Whatt, Vprj, beta, Sc);
    k_step_c<<<128, 256, 0, stream>>>(Sc, Vbuf, Ct);
    k_step_d<<<8, 256, 0, stream>>>(t, X, Hb, Ct, WOP, Ebf, lab);
  }
}